// Round 3
// baseline (210.661 us; speedup 1.0000x reference)
//
#include <hip/hip_runtime.h>

// Inputs: [32,3,512,512] f32; pooled grid 128x128 per image.
#define HH 512
#define WW 512
#define PH 128
#define PW 128
#define CC 3

typedef float f32x4 __attribute__((ext_vector_type(4)));

// R7b: copy-like streaming pool (resubmit of R7 — round 2 was an infra
// failure, "container failed twice", with no counters; source re-audited,
// indices verified, no hang hazards: uniform __syncthreads, flat grid).
//
// Theory A (stream fragmentation): R0-R6 all walked 6 interleaved strided
// streams per wave (3ch x 2 arrays, 1KB chunks at 2KB stride) -> HBM
// row-buffer thrash caps reads at ~2.9 TB/s. This kernel makes each block
// stream 6 SEQUENTIAL contiguous 16KB plane-chunks (one active stream at a
// time; __syncthreads per chunk pins the 4 waves inside one 16KB window and
// stops the compiler hoisting all 24 loads into one burst), with plain
// cached dwordx4 loads -- structurally identical to m13's 6.29 TB/s copy.
//
// Block bid owns pooled rows {2*bid, 2*bid+1} of image bid/64 -> 8
// consecutive image rows x full width x 6 planes = 96KB sequential traffic.
// Thread t: half = t>>7 picks row parity, pj = t&127 picks pooled column.
// Per plane: 4 loads (rows +{0,2,4,6}+half), thread-local accumulate with
// sign (+orig, -enh). Final: LDS combine (pj, pj+128) -> g.
__global__ void __launch_bounds__(256, 8)
pool_diff_kernel(const float* __restrict__ orig,
                 const float* __restrict__ enh,
                 float* __restrict__ g) {
    const int bid  = blockIdx.x;        // 0..2047
    const int t    = threadIdx.x;       // 0..255
    const int half = t >> 7;            // row parity within pair
    const int pj   = t & 127;           // pooled column

    const int b    = bid >> 6;          // image index 0..31
    const int pr0  = (bid & 63) * 2;    // first pooled row of this block
    const int row0 = pr0 * 4;           // first image row (8 rows per block)

    __shared__ float lds[2][256];

    float acc0 = 0.0f, acc1 = 0.0f;

    const size_t img     = (size_t)HH * WW;                       // 262144
    const size_t rowbase = (size_t)row0 * WW + (size_t)pj * 4;

#pragma unroll
    for (int s = 0; s < 6; ++s) {
        const float* src = (s < 3) ? orig : enh;
        const int    c   = (s < 3) ? s : s - 3;
        const float* p   = src + ((size_t)b * CC + c) * img + rowbase
                               + (size_t)half * WW;
        // Rows row0 + {0,2,4,6} + half: block covers the full 16KB chunk.
        f32x4 v0 = *(const f32x4*)(p);
        f32x4 v1 = *(const f32x4*)(p + 2 * WW);
        f32x4 v2 = *(const f32x4*)(p + 4 * WW);
        f32x4 v3 = *(const f32x4*)(p + 6 * WW);
        const float s0 = (v0.x + v0.y) + (v0.z + v0.w);
        const float s1 = (v1.x + v1.y) + (v1.z + v1.w);
        const float s2 = (v2.x + v2.y) + (v2.z + v2.w);
        const float s3 = (v3.x + v3.y) + (v3.z + v3.w);
        if (s < 3) { acc0 += s0 + s1; acc1 += s2 + s3; }
        else       { acc0 -= s0 + s1; acc1 -= s2 + s3; }
        // Keep all 4 waves inside one plane-chunk; also a compiler fence so
        // the 6 plane streams stay sequential instead of being hoisted into
        // one 24-load multi-stream burst.
        __syncthreads();
    }

    lds[0][t] = acc0;
    lds[1][t] = acc1;
    __syncthreads();

    if (t < 128) {
        const float v = (lds[0][t] + lds[0][t + 128]) * (1.0f / 48.0f);
        g[((size_t)b * PH + pr0) * PW + t] = v;
    } else {
        const int tj = t - 128;
        const float v = (lds[1][tj] + lds[1][t]) * (1.0f / 48.0f);
        g[((size_t)b * PH + (pr0 + 1)) * PW + tj] = v;
    }
}

// Kernel 2: loss[i,j] = sum over {l,r,u,d} of (g[i,j] - g_pad[neighbor])^2
// Zero padding: out-of-bounds neighbor contributes 0 (so diff = g[i,j]).
__global__ void __launch_bounds__(256)
stencil_loss_kernel(const float* __restrict__ g,
                    float* __restrict__ out, int total) {
    int idx = blockIdx.x * blockDim.x + threadIdx.x;
    if (idx >= total) return;
    int j = idx & (PW - 1);
    int i = (idx >> 7) & (PH - 1);

    float c = g[idx];
    float l = (j > 0)      ? g[idx - 1]  : 0.0f;
    float r = (j < PW - 1) ? g[idx + 1]  : 0.0f;
    float u = (i > 0)      ? g[idx - PW] : 0.0f;
    float d = (i < PH - 1) ? g[idx + PW] : 0.0f;

    float dl = c - l, dr = c - r, du = c - u, dd = c - d;
    __builtin_nontemporal_store(dl * dl + dr * dr + du * du + dd * dd, out + idx);
}

extern "C" void kernel_launch(void* const* d_in, const int* in_sizes, int n_in,
                              void* d_out, int out_size, void* d_ws, size_t ws_size,
                              hipStream_t stream) {
    const float* orig = (const float*)d_in[0];
    const float* enh  = (const float*)d_in[1];
    float* out = (float*)d_out;
    float* g   = (float*)d_ws;  // 32*128*128 floats = 2 MB scratch

    const int batch = in_sizes[0] / (CC * HH * WW);   // 32
    const int total = batch * PH * PW;                // 524288

    // One block per pooled-row pair: 32 images * 64 pairs = 2048 blocks.
    pool_diff_kernel<<<batch * 64, 256, 0, stream>>>(orig, enh, g);

    const int block = 256;
    const int grid = (total + block - 1) / block;     // 2048
    stencil_loss_kernel<<<grid, block, 0, stream>>>(g, out, total);
}